// Round 6
// baseline (170.490 us; speedup 1.0000x reference)
//
#include <hip/hip_runtime.h>
#include <hip/hip_bf16.h>

typedef __attribute__((ext_vector_type(8))) short short8;   // 8 bf16 (MFMA A/B frag)
typedef __attribute__((ext_vector_type(4))) float floatx4;  // MFMA C/D frag
typedef unsigned int u32;

#define D_DIM 256
#define TCOLS 32      // tile width (cols per epilogue chunk)
#define TILES 8       // tiles per block -> 256 cols/block
#define IDX_BITS 0x1FFFu      // 13-bit index payload (N=M=8192)
#define VAL_MASK 0xFFFFE000u  // truncated value bits (sim+2 positive -> raw bits monotone)

// ---------- helpers ----------

__device__ inline unsigned short f2bf_rne(float f) {
  u32 u = __float_as_uint(f);
  u32 r = (u + 0x7FFFu + ((u >> 16) & 1u)) >> 16;
  return (unsigned short)r;
}

__device__ inline u32 umax(u32 a, u32 b) { return a > b ? a : b; }

// ---------- kernels ----------

// One launch, both inputs. A -> row-major At[row][256] bf16.
// B -> FRAGMENT-ORDERED Bt2: for col-group g (32 cols), the b128 payload of
// MFMA B-frag (kc, j, lane) lives at u16 offset
//     g*8192 + (kc*2 + j)*512 + lane*8          (lane = quad*16 + l15)
// so each GEMM B-frag load is one contiguous 1KB/wave global read from L2.
// Element map: col c (=j*16+l15 within group), feat f (kc=f>>5, q=(f>>3)&3):
//     off = (c>>5)*8192 + (f>>5)*1024 + ((c>>4)&1)*512 + ((f>>3)&3)*128
//           + (c&15)*8 + (f&7)
__global__ __launch_bounds__(256) void transpose_cast2(const float* __restrict__ d0,
                                                       const float* __restrict__ d1,
                                                       unsigned short* __restrict__ At,
                                                       unsigned short* __restrict__ Bt2,
                                                       int N, int M,
                                                       u32* __restrict__ best, int init_n) {
  __shared__ alignas(16) unsigned short tile[64 * 132];  // 16.9 KB, pad->2-way reads
  const int tid = threadIdx.x;
  const int bx = blockIdx.x;
  const int nblkA = N / 64;       // pass N=0 to do B only (fallback path)
  const bool isA = bx < nblkA;
  const float* src = isA ? d0 : d1;
  const int C = isA ? N : M;
  const int gd0 = (isA ? bx : bx - nblkA) * 64;
  const int d = tid & 63;
  const int fy = blockIdx.y;  // feature half: 0 or 1
#pragma unroll
  for (int k = 0; k < 32; ++k) {
    int fl = (tid >> 6) + 4 * k;  // 0..127 within the half
    float v = src[(size_t)(fy * 128 + fl) * C + gd0 + d];
    tile[d * 132 + fl] = f2bf_rne(v);
  }
  __syncthreads();
  if (isA) {
#pragma unroll
    for (int c = 0; c < 4; ++c) {
      int slot = c * 256 + tid;
      int dd = slot >> 4, f8 = slot & 15;
      short8 o = *(const short8*)(tile + dd * 132 + f8 * 8);
      *(short8*)(At + (size_t)(gd0 + dd) * D_DIM + fy * 128 + f8 * 8) = o;
    }
  } else {
#pragma unroll
    for (int c = 0; c < 4; ++c) {
      int slot = c * 256 + tid;
      int dd = slot & 63;            // col within block
      int f8l = c * 4 + (tid >> 6);  // 8-feat chunk within half, 0..15
      int f8g = fy * 16 + f8l;       // global 8-feat chunk = (kc,q): one b128 payload
      short8 o = *(const short8*)(tile + dd * 132 + f8l * 8);
      size_t off = (size_t)((gd0 + dd) >> 5) * 8192 + (size_t)(f8g >> 2) * 1024 +
                   (size_t)((dd >> 4) & 1) * 512 + (f8g & 3) * 128 + (dd & 15) * 8;
      *(short8*)(Bt2 + off) = o;
    }
  }
  if (fy == 0) {
    int i = bx * 256 + tid;
    if (i < init_n) best[i] = 0u;
  }
}

// GEMM + fused argmax, direct-from-L2 B frags (R5 structure), occupancy
// redesign. OCCUPANCY MODEL (fits R2/R3/R5 exactly): reported VGPR_Count
// EXCLUDES AGPRs; HW wave slots quantize power-of-2: waves/SIMD =
// 8/4/2/1 at total<=64/<=128/<=256/>256. R2(192)/R5(160) -> 2 waves ->
// identical 52us at MfmaUtil 24% regardless of LDS/barrier structure:
// 2 waves/SIMD can't cover ~200cy L2 latency. 4 waves needs total<=128.
// Ledger: af[2][8]=64 (32 rows/wave!) + bf[2]=16 + acc[2][2]=16 + rbk[8]=8
// + addr/temps ~16 => ~120. NO reg cap (R1/R4: capping below floor = spill
// catastrophe; worst case here is compiler lands >128 -> flat 52us round).
// Latency arithmetic at 4 waves/SIMD: per kc, 4 MFMA = 78cy issue; 4 waves
// give 312cy matrix work per ~200-300cy load window -> pipe ~saturated.
// acc init = +2.0: outputs sim+2 in [1,3) -> raw bits monotone unsigned.
template <bool PRECAST>
__global__ __launch_bounds__(256) void gemm_reduce(const float* __restrict__ A,
                                                   const unsigned short* __restrict__ At,
                                                   const unsigned short* __restrict__ Bt2,
                                                   u32* __restrict__ best01,
                                                   u32* __restrict__ best10,
                                                   int N, int M) {
  __shared__ u32 colbest[TILES * TCOLS];  // 1 KB — the only LDS

  const int tid  = threadIdx.x;
  const int wave = tid >> 6;
  const int lane = tid & 63;
  const int quad = lane >> 4;
  const int l15  = lane & 15;

  // XCD-chunked decode: y-stripe constant per XCD (bijective when yB%8==0)
  const int xB = N >> 7, yB = M >> 8;   // 128 rows/block, 256 cols/block
  const int bid = blockIdx.x;
  int x, y;
  if ((yB & 7) == 0) {
    int c = bid & 7, k = bid >> 3;
    x = k % xB;
    y = c * (yB >> 3) + k / xB;
  } else {
    x = bid % xB;
    y = bid / xB;
  }
  const int n0  = x * 128;
  const int mg0 = y * (TILES * TCOLS);
  const int rbase = n0 + wave * 32;  // 32 rows per wave

  colbest[tid] = 0u;  // TILES*TCOLS == 256 == blockDim

  // A fragments: wave's 32 rows x full K=256 = 64 VGPR.
  short8 af[2][8];
  if constexpr (PRECAST) {
#pragma unroll
    for (int t = 0; t < 2; ++t) {
      const unsigned short* ap = At + (size_t)(rbase + t * 16 + l15) * D_DIM + quad * 8;
#pragma unroll
      for (int kc = 0; kc < 8; ++kc)
        af[t][kc] = *(const short8*)(ap + kc * 32);
    }
  } else {  // fallback: inline cast from f32 [256][N]
#pragma unroll
    for (int t = 0; t < 2; ++t)
#pragma unroll
      for (int kc = 0; kc < 8; ++kc) {
        const int row = rbase + t * 16 + l15;
        const int kb = kc * 32 + quad * 8;
        short8 o;
#pragma unroll
        for (int u = 0; u < 8; ++u)
          o[u] = (short)f2bf_rne(A[(size_t)(kb + u) * N + row]);
        af[t][kc] = o;
      }
  }

  // B-frag base: per-lane address inside fragment-ordered Bt2
  const unsigned short* bp = Bt2 + (size_t)(mg0 >> 5) * 8192 + (size_t)lane * 8;

  u32 rbk[8];
#pragma unroll
  for (int s = 0; s < 8; ++s) rbk[s] = 0u;
  const u32 rp0 = 0x1FFFu - (u32)(rbase + quad * 4);  // rowpay(i,r) = rp0 - 16i - r

  __syncthreads();  // colbest init visible (only barrier before the end)

  for (int mt = 0; mt < TILES; ++mt) {
    const unsigned short* bpt = bp + (size_t)mt * 8192;
    floatx4 acc[2][2];
#pragma unroll
    for (int i = 0; i < 2; ++i)
#pragma unroll
      for (int j = 0; j < 2; ++j)
        acc[i][j] = (floatx4){2.0f, 2.0f, 2.0f, 2.0f};  // bias: outputs = sim+2 > 0

    // K loop: single rotating bf pair; compiler pipelines to its reg budget
#pragma unroll
    for (int kc = 0; kc < 8; ++kc) {
      short8 bf0 = *(const short8*)(bpt + (kc * 2 + 0) * 512);
      short8 bf1 = *(const short8*)(bpt + (kc * 2 + 1) * 512);
      acc[0][0] = __builtin_amdgcn_mfma_f32_16x16x32_bf16(af[0][kc], bf0, acc[0][0], 0, 0, 0);
      acc[1][0] = __builtin_amdgcn_mfma_f32_16x16x32_bf16(af[1][kc], bf0, acc[1][0], 0, 0, 0);
      acc[0][1] = __builtin_amdgcn_mfma_f32_16x16x32_bf16(af[0][kc], bf1, acc[0][1], 0, 0, 0);
      acc[1][1] = __builtin_amdgcn_mfma_f32_16x16x32_bf16(af[1][kc], bf1, acc[1][1], 0, 0, 0);
    }

    // ---- epilogue. C/D map: col = j*16 + l15, row = i*16 + quad*4 + r
    const int m0 = mg0 + mt * TCOLS;
    u32 cb[2] = {0u, 0u};
    u32 colpay[2] = {0x1FFFu - (u32)(m0 + l15), 0x1FFFu - (u32)(m0 + 16 + l15)};
#pragma unroll
    for (int i = 0; i < 2; ++i)
#pragma unroll
      for (int r = 0; r < 4; ++r) {
        u32 rp = rp0 - (u32)(i * 16 + r);
        u32 rb = rbk[i * 4 + r];
#pragma unroll
        for (int j = 0; j < 2; ++j) {
          u32 u = __float_as_uint(acc[i][j][r]) & VAL_MASK;  // positive -> monotone
          rb = umax(rb, u | colpay[j]);
          cb[j] = umax(cb[j], u | rp);
        }
        rbk[i * 4 + r] = rb;
      }
    // col-argmax: butterfly over the 4 quads, then LDS atomic (no barrier)
#pragma unroll
    for (int j = 0; j < 2; ++j) {
      u32 b = cb[j];
      b = umax(b, (u32)__shfl_xor((int)b, 16, 64));
      b = umax(b, (u32)__shfl_xor((int)b, 32, 64));
      if (quad == 0) atomicMax(&colbest[mt * TCOLS + j * 16 + l15], b);
    }
  }

  // ---- final row reduction: butterfly over l15, one atomic per row
#pragma unroll
  for (int i = 0; i < 2; ++i)
#pragma unroll
    for (int r = 0; r < 4; ++r) {
      u32 b = rbk[i * 4 + r];
      b = umax(b, (u32)__shfl_xor((int)b, 1, 64));
      b = umax(b, (u32)__shfl_xor((int)b, 2, 64));
      b = umax(b, (u32)__shfl_xor((int)b, 4, 64));
      b = umax(b, (u32)__shfl_xor((int)b, 8, 64));
      if (l15 == 0) atomicMax(&best01[rbase + i * 16 + quad * 4 + r], b);
    }

  // ---- col flush: wait all waves' colbest LDS atomics, then one global each
  __syncthreads();
  atomicMax(&best10[mg0 + tid], colbest[tid]);
}

__global__ void finalize(const u32* __restrict__ best01, const u32* __restrict__ best10,
                         float* __restrict__ out, int N) {
  int n = blockIdx.x * blockDim.x + threadIdx.x;
  if (n >= N) return;
  u32 k = best01[n];
  int idx01 = (int)((~k) & IDX_BITS);
  float sim = __uint_as_float(k & VAL_MASK) - 2.0f;  // undo +2 bias
  int idx10 = (int)((~best10[idx01]) & IDX_BITS);
  float dist = 2.0f - 2.0f * sim;             // squared L2 for unit vectors
  bool ok = (idx10 == n) && (dist <= 0.64f);  // mutual NN + thresh^2
  out[n]     = ok ? (float)idx01 : -1.0f;
  out[N + n] = ok ? 1.5f - sim : 0.0f;        // (dist+1)/2
}

// ---------- launcher ----------

extern "C" void kernel_launch(void* const* d_in, const int* in_sizes, int n_in,
                              void* d_out, int out_size, void* d_ws, size_t ws_size,
                              hipStream_t stream) {
  (void)n_in; (void)out_size;
  const float* d0 = (const float*)d_in[0];  // [256][N]
  const float* d1 = (const float*)d_in[1];  // [256][M]
  const int N = in_sizes[0] / D_DIM;        // 8192
  const int M = in_sizes[1] / D_DIM;        // 8192

  u32* best01 = (u32*)d_ws;                            // N u32
  u32* best10 = best01 + N;                            // M u32
  unsigned short* At  = (unsigned short*)(best10 + M); // [N][256] bf16
  unsigned short* Bt2 = At + (size_t)N * D_DIM;        // [M/32][frag-ordered] bf16
  float* out = (float*)d_out;

  const int nBlocks = (N / 128) * (M / 256);
  const size_t need = (size_t)(N + M) * sizeof(u32) +
                      (size_t)(N + M) * D_DIM * sizeof(unsigned short);

  if (ws_size >= need) {
    hipLaunchKernelGGL(transpose_cast2, dim3((N + M) / 64, 2), dim3(256), 0, stream,
                       d0, d1, At, Bt2, N, M, best01, N + M);
    hipLaunchKernelGGL((gemm_reduce<true>), dim3(nBlocks), dim3(256), 0, stream,
                       d0, At, Bt2, best01, best10, N, M);
  } else {
    // ws too small for At: B-only frag-precast (N=0 -> all blocks do B),
    // inline A cast in the GEMM
    unsigned short* BtF = (unsigned short*)(best10 + M);
    hipLaunchKernelGGL(transpose_cast2, dim3(M / 64, 2), dim3(256), 0, stream,
                       d1, d1, BtF, BtF, 0, M, best01, N + M);
    hipLaunchKernelGGL((gemm_reduce<false>), dim3(nBlocks), dim3(256), 0, stream,
                       d0, BtF, BtF, best01, best10, N, M);
  }
  hipLaunchKernelGGL(finalize, dim3(N / 256), dim3(256), 0, stream, best01, best10, out, N);
}

// Round 7
// 157.300 us; speedup vs baseline: 1.0839x; 1.0839x over previous
//
#include <hip/hip_runtime.h>
#include <hip/hip_bf16.h>

typedef __attribute__((ext_vector_type(8))) short short8;   // 8 bf16 (MFMA A/B frag)
typedef __attribute__((ext_vector_type(4))) float floatx4;  // MFMA C/D frag
typedef unsigned int u32;

#define D_DIM 256
#define TCOLS 32      // cols per epilogue tile
#define BTILES 4      // tiles per block -> 128 cols/block; B panel = 64 KB LDS
#define IDX_BITS 0x1FFFu      // 13-bit index payload (N=M=8192)
#define VAL_MASK 0xFFFFE000u  // truncated value bits (sim+2 positive -> raw bits monotone)

// ---------- helpers ----------

__device__ inline unsigned short f2bf_rne(float f) {
  u32 u = __float_as_uint(f);
  u32 r = (u + 0x7FFFu + ((u >> 16) & 1u)) >> 16;
  return (unsigned short)r;
}

__device__ inline u32 umax(u32 a, u32 b) { return a > b ? a : b; }

__device__ inline void async_ld16(const void* g, void* l) {
  __builtin_amdgcn_global_load_lds((const __attribute__((address_space(1))) void*)g,
                                   (__attribute__((address_space(3))) void*)l, 16, 0, 0);
}

// ---------- kernels ----------

// One launch, both inputs. A -> row-major At[row][256] bf16.
// B -> FRAGMENT-ORDERED Bt2: for col-group g (32 cols), the b128 payload of
// MFMA B-frag (kc, j, lane) lives at u16 offset
//     g*8192 + (kc*2 + j)*512 + lane*8          (lane = quad*16 + l15)
// Consumed in exactly this order by the GEMM -> global_load_lds staging is
// LINEAR (wave-uniform base + slot*16) and every ds_read_b128 is contiguous
// (0 bank conflicts, verified R5: SQ_LDS_BANK_CONFLICT = 0 with this layout).
// Element map: col c (=j*16+l15 within group), feat f:
//     off = (c>>5)*8192 + (f>>5)*1024 + ((c>>4)&1)*512 + ((f>>3)&3)*128
//           + (c&15)*8 + (f&7)
__global__ __launch_bounds__(256) void transpose_cast2(const float* __restrict__ d0,
                                                       const float* __restrict__ d1,
                                                       unsigned short* __restrict__ At,
                                                       unsigned short* __restrict__ Bt2,
                                                       int N, int M,
                                                       u32* __restrict__ best, int init_n) {
  __shared__ alignas(16) unsigned short tile[64 * 132];  // 16.9 KB, pad->2-way reads
  const int tid = threadIdx.x;
  const int bx = blockIdx.x;
  const int nblkA = N / 64;       // pass N=0 to do B only (fallback path)
  const bool isA = bx < nblkA;
  const float* src = isA ? d0 : d1;
  const int C = isA ? N : M;
  const int gd0 = (isA ? bx : bx - nblkA) * 64;
  const int d = tid & 63;
  const int fy = blockIdx.y;  // feature half: 0 or 1
#pragma unroll
  for (int k = 0; k < 32; ++k) {
    int fl = (tid >> 6) + 4 * k;  // 0..127 within the half
    float v = src[(size_t)(fy * 128 + fl) * C + gd0 + d];
    tile[d * 132 + fl] = f2bf_rne(v);
  }
  __syncthreads();
  if (isA) {
#pragma unroll
    for (int c = 0; c < 4; ++c) {
      int slot = c * 256 + tid;
      int dd = slot >> 4, f8 = slot & 15;
      short8 o = *(const short8*)(tile + dd * 132 + f8 * 8);
      *(short8*)(At + (size_t)(gd0 + dd) * D_DIM + fy * 128 + f8 * 8) = o;
    }
  } else {
#pragma unroll
    for (int c = 0; c < 4; ++c) {
      int slot = c * 256 + tid;
      int dd = slot & 63;            // col within block
      int f8l = c * 4 + (tid >> 6);  // 8-feat chunk within half, 0..15
      int f8g = fy * 16 + f8l;       // global 8-feat chunk: one b128 payload
      short8 o = *(const short8*)(tile + dd * 132 + f8l * 8);
      size_t off = (size_t)((gd0 + dd) >> 5) * 8192 + (size_t)(f8g >> 2) * 1024 +
                   (size_t)((dd >> 4) & 1) * 512 + (f8g & 3) * 128 + (dd & 15) * 8;
      *(short8*)(Bt2 + off) = o;
    }
  }
  if (fy == 0) {
    int i = bx * 256 + tid;
    if (i < init_n) best[i] = 0u;
  }
}

// GEMM + fused argmax, R7 "stage-once, free-run" structure.
// Lesson ledger: R1/R4 = capping regs below floor -> spill catastrophe;
// R3 = >256 total regs -> 1 wave/SIMD; R4/R5/R6 = occupancy is NOT
// controllably movable above 2 waves/SIMD for this workload (compiler AGPR
// use defeats the ledger); every 2-waves/SIMD schedule variant = 52us with
// MfmaUtil 24% -- stalled on the per-kc B-load (L2 ~300-600cy) -> MFMA
// dependency that shallow reg-pipelining can't cover.
// This version removes the in-loop load latency entirely:
//   - block = 256 rows x 128 cols; the block's WHOLE B panel (128 cols x
//     K=256 = 64 KB) is staged into LDS once via linear global_load_lds
//     (frag-ordered Bt2 -> dest offset = slot*16, wave-uniform-base safe).
//   - ONE __syncthreads after staging; ZERO barriers in the main loop;
//     waves free-run over 4 col-tiles: 8 kc x {2 ds_read_b128 + 8 MFMA}.
//     ds latency ~120cy < 8-MFMA issue chain ~155cy at 2 waves/SIMD ->
//     self-covering. LDS pipe: 8 waves x 16 reads x 12cy = 1536cy < matrix
//     2483cy per tile-group.
//   - col-argmax: direct global atomicMax (R0-verified), fire-and-forget --
//     no colbest LDS, no tail barrier.
//   - 2 blocks/CU (2x64KB=128KB<=160KB): one block's staging hides under
//     the other's compute.
// acc init = +2.0: outputs sim+2 in [1,3) -> raw bits monotone unsigned.
template <bool PRECAST>
__global__ __launch_bounds__(256) void gemm_reduce(const float* __restrict__ A,
                                                   const unsigned short* __restrict__ At,
                                                   const unsigned short* __restrict__ Bt2,
                                                   u32* __restrict__ best01,
                                                   u32* __restrict__ best10,
                                                   int N, int M) {
  __shared__ alignas(16) unsigned short sB[BTILES * TCOLS * D_DIM];  // 65536 B exactly

  const int tid  = threadIdx.x;
  const int wave = tid >> 6;
  const int lane = tid & 63;
  const int quad = lane >> 4;
  const int l15  = lane & 15;

  // XCD-chunked decode: col-stripe constant per XCD (bijective: yB%8==0)
  const int xB = N >> 8, yB = M >> 7;   // 256 rows/block, 128 cols/block
  const int bid = blockIdx.x;
  int x, y;
  if ((yB & 7) == 0) {
    int c = bid & 7, k = bid >> 3;
    x = k % xB;
    y = c * (yB >> 3) + k / xB;
  } else {
    x = bid % xB;
    y = bid / xB;
  }
  const int n0  = x * 256;
  const int mg0 = y * (BTILES * TCOLS);
  const int rbase = n0 + wave * 64;  // 64 rows per wave

  // ---- stage the whole B panel: 64 KB, 16 linear gload_lds per thread.
  // Issued FIRST so its latency overlaps the A-fragment loads below.
  {
    const unsigned short* src = Bt2 + (size_t)(mg0 >> 5) * 8192;
#pragma unroll
    for (int c = 0; c < 16; ++c) {
      int slot = c * 256 + tid;
      async_ld16(src + (size_t)slot * 8, sB + (size_t)slot * 8);
    }
  }

  // A fragments: wave's 64 rows x full K=256 = 128 VGPR.
  short8 af[4][8];
  if constexpr (PRECAST) {
#pragma unroll
    for (int t = 0; t < 4; ++t) {
      const unsigned short* ap = At + (size_t)(rbase + t * 16 + l15) * D_DIM + quad * 8;
#pragma unroll
      for (int kc = 0; kc < 8; ++kc)
        af[t][kc] = *(const short8*)(ap + kc * 32);
    }
  } else {  // fallback: inline cast from f32 [256][N]
#pragma unroll
    for (int t = 0; t < 4; ++t)
#pragma unroll
      for (int kc = 0; kc < 8; ++kc) {
        const int row = rbase + t * 16 + l15;
        const int kb = kc * 32 + quad * 8;
        short8 o;
#pragma unroll
        for (int u = 0; u < 8; ++u)
          o[u] = (short)f2bf_rne(A[(size_t)(kb + u) * N + row]);
        af[t][kc] = o;
      }
  }

  u32 rbk[16];
#pragma unroll
  for (int s = 0; s < 16; ++s) rbk[s] = 0u;
  const u32 rp0 = 0x1FFFu - (u32)(rbase + quad * 4);  // rowpay(i,r) = rp0 - 16i - r

  __syncthreads();  // staging complete (the ONLY barrier in this kernel)

  for (int tt = 0; tt < BTILES; ++tt) {
    const unsigned short* bpt = sB + tt * 8192 + lane * 8;  // frag-ordered LDS
    floatx4 acc[4][2];
#pragma unroll
    for (int i = 0; i < 4; ++i)
#pragma unroll
      for (int j = 0; j < 2; ++j)
        acc[i][j] = (floatx4){2.0f, 2.0f, 2.0f, 2.0f};  // bias: outputs = sim+2 > 0

#pragma unroll
    for (int kc = 0; kc < 8; ++kc) {
      short8 bf0 = *(const short8*)(bpt + (kc * 2 + 0) * 512);  // ds_read_b128
      short8 bf1 = *(const short8*)(bpt + (kc * 2 + 1) * 512);  // contiguous: 0 conflicts
      acc[0][0] = __builtin_amdgcn_mfma_f32_16x16x32_bf16(af[0][kc], bf0, acc[0][0], 0, 0, 0);
      acc[1][0] = __builtin_amdgcn_mfma_f32_16x16x32_bf16(af[1][kc], bf0, acc[1][0], 0, 0, 0);
      acc[2][0] = __builtin_amdgcn_mfma_f32_16x16x32_bf16(af[2][kc], bf0, acc[2][0], 0, 0, 0);
      acc[3][0] = __builtin_amdgcn_mfma_f32_16x16x32_bf16(af[3][kc], bf0, acc[3][0], 0, 0, 0);
      acc[0][1] = __builtin_amdgcn_mfma_f32_16x16x32_bf16(af[0][kc], bf1, acc[0][1], 0, 0, 0);
      acc[1][1] = __builtin_amdgcn_mfma_f32_16x16x32_bf16(af[1][kc], bf1, acc[1][1], 0, 0, 0);
      acc[2][1] = __builtin_amdgcn_mfma_f32_16x16x32_bf16(af[2][kc], bf1, acc[2][1], 0, 0, 0);
      acc[3][1] = __builtin_amdgcn_mfma_f32_16x16x32_bf16(af[3][kc], bf1, acc[3][1], 0, 0, 0);
    }

    // ---- epilogue. C/D map: col = j*16 + l15, row = i*16 + quad*4 + r
    const int m0 = mg0 + tt * TCOLS;
    u32 cb[2] = {0u, 0u};
    u32 colpay[2] = {0x1FFFu - (u32)(m0 + l15), 0x1FFFu - (u32)(m0 + 16 + l15)};
#pragma unroll
    for (int i = 0; i < 4; ++i)
#pragma unroll
      for (int r = 0; r < 4; ++r) {
        u32 rp = rp0 - (u32)(i * 16 + r);
        u32 rb = rbk[i * 4 + r];
#pragma unroll
        for (int j = 0; j < 2; ++j) {
          u32 u = __float_as_uint(acc[i][j][r]) & VAL_MASK;  // positive -> monotone
          rb = umax(rb, u | colpay[j]);
          cb[j] = umax(cb[j], u | rp);
        }
        rbk[i * 4 + r] = rb;
      }
    // col-argmax: butterfly over the 4 quads, then direct global atomic
    // (fire-and-forget: nothing waits on it, latency fully hidden)
#pragma unroll
    for (int j = 0; j < 2; ++j) {
      u32 b = cb[j];
      b = umax(b, (u32)__shfl_xor((int)b, 16, 64));
      b = umax(b, (u32)__shfl_xor((int)b, 32, 64));
      if (quad == 0) atomicMax(&best10[m0 + j * 16 + l15], b);
    }
  }

  // ---- final row reduction: butterfly over l15, one atomic per row
#pragma unroll
  for (int i = 0; i < 4; ++i)
#pragma unroll
    for (int r = 0; r < 4; ++r) {
      u32 b = rbk[i * 4 + r];
      b = umax(b, (u32)__shfl_xor((int)b, 1, 64));
      b = umax(b, (u32)__shfl_xor((int)b, 2, 64));
      b = umax(b, (u32)__shfl_xor((int)b, 4, 64));
      b = umax(b, (u32)__shfl_xor((int)b, 8, 64));
      if (l15 == 0) atomicMax(&best01[rbase + i * 16 + quad * 4 + r], b);
    }
}

__global__ void finalize(const u32* __restrict__ best01, const u32* __restrict__ best10,
                         float* __restrict__ out, int N) {
  int n = blockIdx.x * blockDim.x + threadIdx.x;
  if (n >= N) return;
  u32 k = best01[n];
  int idx01 = (int)((~k) & IDX_BITS);
  float sim = __uint_as_float(k & VAL_MASK) - 2.0f;  // undo +2 bias
  int idx10 = (int)((~best10[idx01]) & IDX_BITS);
  float dist = 2.0f - 2.0f * sim;             // squared L2 for unit vectors
  bool ok = (idx10 == n) && (dist <= 0.64f);  // mutual NN + thresh^2
  out[n]     = ok ? (float)idx01 : -1.0f;
  out[N + n] = ok ? 1.5f - sim : 0.0f;        // (dist+1)/2
}

// ---------- launcher ----------

extern "C" void kernel_launch(void* const* d_in, const int* in_sizes, int n_in,
                              void* d_out, int out_size, void* d_ws, size_t ws_size,
                              hipStream_t stream) {
  (void)n_in; (void)out_size;
  const float* d0 = (const float*)d_in[0];  // [256][N]
  const float* d1 = (const float*)d_in[1];  // [256][M]
  const int N = in_sizes[0] / D_DIM;        // 8192
  const int M = in_sizes[1] / D_DIM;        // 8192

  u32* best01 = (u32*)d_ws;                            // N u32
  u32* best10 = best01 + N;                            // M u32
  unsigned short* At  = (unsigned short*)(best10 + M); // [N][256] bf16
  unsigned short* Bt2 = At + (size_t)N * D_DIM;        // [M/32][frag-ordered] bf16
  float* out = (float*)d_out;

  const int nBlocks = (N / 256) * (M / 128);
  const size_t need = (size_t)(N + M) * sizeof(u32) +
                      (size_t)(N + M) * D_DIM * sizeof(unsigned short);

  if (ws_size >= need) {
    hipLaunchKernelGGL(transpose_cast2, dim3((N + M) / 64, 2), dim3(256), 0, stream,
                       d0, d1, At, Bt2, N, M, best01, N + M);
    hipLaunchKernelGGL((gemm_reduce<true>), dim3(nBlocks), dim3(256), 0, stream,
                       d0, At, Bt2, best01, best10, N, M);
  } else {
    // ws too small for At: B-only frag-precast (N=0 -> all blocks do B),
    // inline A cast in the GEMM
    unsigned short* BtF = (unsigned short*)(best10 + M);
    hipLaunchKernelGGL(transpose_cast2, dim3(M / 64, 2), dim3(256), 0, stream,
                       d1, d1, BtF, BtF, 0, M, best01, N + M);
    hipLaunchKernelGGL((gemm_reduce<false>), dim3(nBlocks), dim3(256), 0, stream,
                       d0, BtF, BtF, best01, best10, N, M);
  }
  hipLaunchKernelGGL(finalize, dim3(N / 256), dim3(256), 0, stream, best01, best10, out, N);
}